// Round 6
// baseline (296.609 us; speedup 1.0000x reference)
//
#include <hip/hip_runtime.h>

typedef short s16x8 __attribute__((ext_vector_type(8)));
typedef float f32x4 __attribute__((ext_vector_type(4)));
typedef float f32x16 __attribute__((ext_vector_type(16)));
typedef unsigned u32x4 __attribute__((ext_vector_type(4)));

// ---------- helpers ----------

__device__ __forceinline__ unsigned short bf16bits(float f) {
  // round-to-nearest-even fp32 -> bf16 (finite inputs only)
  unsigned u = __builtin_bit_cast(unsigned, f);
  unsigned rnd = 0x7FFFu + ((u >> 16) & 1u);
  return (unsigned short)((u + rnd) >> 16);
}

__device__ __forceinline__ unsigned pk_bf16(float lo, float hi) {
  // dst[15:0]=bf16(lo), dst[31:16]=bf16(hi), RNE — one VALU op
  unsigned r;
  asm("v_cvt_pk_bf16_f32 %0, %1, %2" : "=v"(r) : "v"(lo), "v"(hi));
  return r;
}

__device__ __forceinline__ void async16(const void* g, void* l) {
  // global -> LDS direct copy, 16B per lane; LDS dest = wave-uniform base + lane*16
  __builtin_amdgcn_global_load_lds((const __attribute__((address_space(1))) void*)g,
                                   (__attribute__((address_space(3))) void*)l, 16, 0, 0);
}

__device__ __forceinline__ f32x4 mfma16(s16x8 a, s16x8 b, f32x4 c) {
  return __builtin_amdgcn_mfma_f32_16x16x32_bf16(a, b, c, 0, 0, 0);
}

__device__ __forceinline__ f32x16 mfma32(s16x8 a, s16x8 b, f32x16 c) {
  return __builtin_amdgcn_mfma_f32_32x32x16_bf16(a, b, c, 0, 0, 0);
}

// XOR-swizzled LDS tile: logical (row, col8) stored at unit row*U + (col8 ^ (row&(U-1)))
__device__ __forceinline__ s16x8 lds_frag(const unsigned short* S, int row, int c8, int U) {
  int unit = row * U + (c8 ^ (row & (U - 1)));
  return *(const s16x8*)(S + unit * 8);
}

// ---------- conversion / transpose kernels ----------

__global__ __launch_bounds__(256) void cvt_f32_bf16(const float4* __restrict__ in,
                                                    unsigned short* __restrict__ out, int n4) {
  int i = blockIdx.x * blockDim.x + threadIdx.x;
  int stride = gridDim.x * blockDim.x;
  for (; i < n4; i += stride) {
    float4 v = in[i];
    uint2 o;
    o.x = pk_bf16(v.x, v.y);
    o.y = pk_bf16(v.z, v.w);
    *(uint2*)(out + (size_t)i * 4) = o;
  }
}

// out[c][r] (bf16) = in[r][c] (fp32); R,C multiples of 32
__global__ __launch_bounds__(256) void transpose_f32_bf16(const float* __restrict__ in,
                                                          unsigned short* __restrict__ out,
                                                          int R, int C) {
  __shared__ float tile[32][33];
  int c0 = blockIdx.x * 32, r0 = blockIdx.y * 32;
  int tx = threadIdx.x, ty = threadIdx.y;  // (32, 8)
  #pragma unroll
  for (int i = 0; i < 32; i += 8)
    tile[ty + i][tx] = in[(size_t)(r0 + ty + i) * C + c0 + tx];
  __syncthreads();
  #pragma unroll
  for (int i = 0; i < 32; i += 8)
    out[(size_t)(c0 + ty + i) * R + r0 + tx] = bf16bits(tile[tx][ty + i]);
}

// V: [64 bh][2048][64] bf16 -> Vt: [64 bh][64][2048] bf16
__global__ __launch_bounds__(256) void transpose_v(const unsigned short* __restrict__ V,
                                                   unsigned short* __restrict__ Vt) {
  __shared__ unsigned short sm[64 * 68];
  int bh = blockIdx.y, kt0 = blockIdx.x * 64;
  const unsigned short* v = V + (size_t)bh * 2048 * 64 + (size_t)kt0 * 64;  // 64x64 tile, contiguous
  unsigned short* vt = Vt + (size_t)bh * 64 * 2048;
  int t = threadIdx.x;
  #pragma unroll
  for (int i = 0; i < 4; ++i) {
    int u = i * 256 + t;        // uint2 index, 4 ushorts each
    int f = u * 4;              // flat = key*64 + d
    int k = f >> 6, d0 = f & 63;
    *(uint2*)&sm[k * 68 + d0] = *(const uint2*)&v[f];
  }
  __syncthreads();
  #pragma unroll
  for (int j = 0; j < 16; ++j) {
    int o = j * 256 + t;        // d*64 + k
    int d = o >> 6, k = o & 63;
    vt[(size_t)d * 2048 + kt0 + k] = sm[k * 68 + d];
  }
}

// ---------- GEMM: C[M,N] = A[M,K] @ Bt[N,K]^T, bf16 in, fp32 acc ----------
// Orientation chosen so M = "packed" output dim: epilogue functor gets 4
// consecutive-m accumulator values per lane (D-layout row axis) -> 8B/16B stores.

template <typename EPI>
__global__ __launch_bounds__(256) void gemm_bt(const unsigned short* __restrict__ A,
                                               const unsigned short* __restrict__ Bt,
                                               int K, EPI epi) {
  __shared__ __align__(16) unsigned short As[128 * 64];
  __shared__ __align__(16) unsigned short Bs[128 * 64];
  const int tid = threadIdx.x, wid = tid >> 6, lane = tid & 63;
  const int quad = lane >> 4, l16 = lane & 15;
  const int bm0 = blockIdx.y * 128, bn0 = blockIdx.x * 128;
  const int wm = (wid & 1) * 64, wn = (wid >> 1) * 64;
  f32x4 acc[4][4] = {};

  for (int kt = 0; kt < K; kt += 64) {
    #pragma unroll
    for (int t = 0; t < 4; ++t) {
      int c = wid * 4 + t;          // chunk 0..15, 1KB each
      int u = c * 64 + lane;        // physical 16B unit
      int row = u >> 3;
      int c8 = (u & 7) ^ (row & 7); // logical col8 (swizzle on fetch side)
      async16(A + (size_t)(bm0 + row) * K + kt + c8 * 8, (char*)As + c * 1024);
      async16(Bt + (size_t)(bn0 + row) * K + kt + c8 * 8, (char*)Bs + c * 1024);
    }
    __syncthreads();  // drains vmcnt before ds_read
    #pragma unroll
    for (int kk = 0; kk < 2; ++kk) {
      s16x8 a[4], b[4];
      #pragma unroll
      for (int i = 0; i < 4; ++i) a[i] = lds_frag(As, wm + i * 16 + l16, kk * 4 + quad, 8);
      #pragma unroll
      for (int j = 0; j < 4; ++j) b[j] = lds_frag(Bs, wn + j * 16 + l16, kk * 4 + quad, 8);
      #pragma unroll
      for (int i = 0; i < 4; ++i)
        #pragma unroll
        for (int j = 0; j < 4; ++j)
          acc[i][j] = mfma16(a[i], b[j], acc[i][j]);
    }
    __syncthreads();
  }
  // epilogue: per (i,j) one call, 4 consecutive m per lane
  #pragma unroll
  for (int i = 0; i < 4; ++i)
    #pragma unroll
    for (int j = 0; j < 4; ++j)
      epi.store4(bm0 + wm + i * 16 + quad * 4, bn0 + wn + j * 16 + l16, acc[i][j]);
}

// QKV (swapped orientation): m = qkv-dim (s*1024 + h*64 + d), n = x-row (b*2048+ns).
// 4 consecutive m = 4 consecutive d -> one 8B store into [bh][ns][64] layout.
struct QKVEpi {
  unsigned short *Q, *K, *V;  // each [64 bh][2048 ns][64 d]
  float qscale;               // hd^-0.5 * log2(e): folds softmax into exp2 domain
  __device__ __forceinline__ void store4(int m0, int n, f32x4 v) const {
    int s = m0 >> 10, h = (m0 >> 6) & 15, d = m0 & 63;
    int b = n >> 11, ns = n & 2047;
    unsigned short* dst = (s == 0) ? Q : ((s == 1) ? K : V);
    float sc = (s == 0) ? qscale : 1.f;
    uint2 o;
    o.x = pk_bf16(v[0] * sc, v[1] * sc);
    o.y = pk_bf16(v[2] * sc, v[3] * sc);
    *(uint2*)&dst[(((size_t)b * 16 + h) * 2048 + ns) * 64 + d] = o;
  }
};

// Proj (swapped orientation): m = out-col, n = x-row. One float4 store + float4 bias.
struct ProjEpi {
  const float* bias;
  float* out;
  __device__ __forceinline__ void store4(int m0, int n, f32x4 v) const {
    float4 b4 = *(const float4*)&bias[m0];
    float4 o = {v[0] + b4.x, v[1] + b4.y, v[2] + b4.z, v[3] + b4.w};
    *(float4*)&out[(size_t)n * 1024 + m0] = o;
  }
};

// ---------- flash attention ----------
// S^T form, register-resident P, max-free softmax, double-buffered staging
// (one barrier per tile), 32 q-rows per wave -> grid 1024 blocks = 4 blocks/CU.
// K/V tiles staged FRAGMENT-MAJOR: LDS unit (chunk*64 + lane) holds exactly the
// 16B fragment that (lane, instr) consumes -> every ds_read_b128 is
// lane-consecutive (zero bank conflicts) and address = base + imm + lane*16.
// Q,K: [64 bh][2048][64] bf16 (Q pre-scaled by hd^-0.5*log2e);  Vt: [64 bh][64][2048]
// O: [4][2048][16][64] bf16.
__global__ __launch_bounds__(256, 4) void flash_attn(const unsigned short* __restrict__ Q,
                                                     const unsigned short* __restrict__ K,
                                                     const unsigned short* __restrict__ Vt,
                                                     unsigned short* __restrict__ O) {
  __shared__ __align__(16) unsigned short Ks[2][8 * 512];  // dbuf, 8 chunks (kf,s) of 64 frags
  __shared__ __align__(16) unsigned short Vs[2][8 * 512];  // dbuf, 8 chunks (ktstep,f)
  const int tid = threadIdx.x, wid = tid >> 6, lane = tid & 63;
  const int l31 = lane & 31, half = lane >> 5;
  const int bh = blockIdx.y, qt = blockIdx.x;
  const unsigned short* Qg = Q + (size_t)bh * 2048 * 64;
  const unsigned short* Kg = K + (size_t)bh * 2048 * 64;
  const unsigned short* Vg = Vt + (size_t)bh * 64 * 2048;
  const int qrow = qt * 128 + wid * 32 + l31;  // this lane's q-row

  // Q as B-operand fragments: B[k=d][n=qrow]; lane holds d = s*16 + half*8 + j
  s16x8 qB[4];
  #pragma unroll
  for (int s = 0; s < 4; ++s)
    qB[s] = *(const s16x8*)&Qg[(size_t)qrow * 64 + s * 16 + half * 8];

  // staging: waves 0,1 stage K chunks 0..7 (kf=c>>2, s=c&3); waves 2,3 stage V
  // chunks 0..7 (ktstep=c>>1, f=c&1). Lane fetches exactly its fragment source.
  const bool isK = wid < 2;
  int sA[4];
  #pragma unroll
  for (int t = 0; t < 4; ++t) {
    int c = (wid & 1) * 4 + t;
    if (isK) sA[t] = ((c >> 2) * 32 + l31) * 64 + ((c & 3) * 2 + half) * 8;
    else     sA[t] = ((c & 1) * 32 + l31) * 2048 + (c >> 1) * 16 + half * 8;
  }

  auto stage = [&](int kt, int buf) {
    const int kb = kt * 64;
    #pragma unroll
    for (int t = 0; t < 4; ++t) {
      int c = (wid & 1) * 4 + t;
      if (isK) async16(Kg + (size_t)kb * 64 + sA[t], (char*)&Ks[buf][0] + c * 1024);
      else     async16(Vg + kb + sA[t],              (char*)&Vs[buf][0] + c * 1024);
    }
  };

  f32x16 oacc[2] = {};  // [f]: O^T[d = f*32 + (r&3)+8*(r>>2)+4*half][qrow]
  float l_i = 0.f;
  const f32x16 fz = {};

  stage(0, 0);
  for (int kt = 0; kt < 32; ++kt) {
    const int cur = kt & 1;
    __syncthreads();  // tile kt visible to all; buf cur^1 free (all done with kt-1)
    if (kt + 1 < 32) stage(kt + 1, cur ^ 1);  // in flight across this tile's compute
    const unsigned short* ks = &Ks[cur][0];
    const unsigned short* vs = &Vs[cur][0];

    #pragma unroll
    for (int kf = 0; kf < 2; ++kf) {  // 32-key chunk: QK -> softmax -> PV
      // S^T = K @ Q^T; A-frag: keys kf*32 + (r&3)+8*(r>>2)+4*half, col = qrow
      f32x16 st;
      {
        s16x8 a = *(const s16x8*)&ks[((kf * 4 + 0) * 64 + lane) * 8];
        st = mfma32(a, qB[0], fz);
      }
      #pragma unroll
      for (int s = 1; s < 4; ++s) {
        s16x8 a = *(const s16x8*)&ks[((kf * 4 + s) * 64 + lane) * 8];
        st = mfma32(a, qB[s], st);
      }
      // max-free softmax (scores bounded; fp32 can't overflow), tree-reduced sum
      float a0 = 0.f, a1 = 0.f, a2 = 0.f, a3 = 0.f;
      #pragma unroll
      for (int r = 0; r < 16; r += 4) {
        float p0 = __builtin_amdgcn_exp2f(st[r + 0]);
        float p1 = __builtin_amdgcn_exp2f(st[r + 1]);
        float p2 = __builtin_amdgcn_exp2f(st[r + 2]);
        float p3 = __builtin_amdgcn_exp2f(st[r + 3]);
        st[r + 0] = p0; st[r + 1] = p1; st[r + 2] = p2; st[r + 3] = p3;
        a0 += p0; a1 += p1; a2 += p2; a3 += p3;
      }
      float rs = (a0 + a1) + (a2 + a3);
      rs += __shfl_xor(rs, 32);
      l_i += rs;
      // pack P to bf16 B-frags (half-swap via dword shuffle) + PV
      #pragma unroll
      for (int t = 0; t < 2; ++t) {  // 16-key step within chunk
        int rb = t * 8;
        unsigned pa0 = pk_bf16(st[rb + 0], st[rb + 1]);
        unsigned pa1 = pk_bf16(st[rb + 2], st[rb + 3]);
        unsigned pb0 = pk_bf16(st[rb + 4], st[rb + 5]);
        unsigned pb1 = pk_bf16(st[rb + 6], st[rb + 7]);
        unsigned s0 = half ? pa0 : pb0;
        unsigned s1 = half ? pa1 : pb1;
        unsigned r0 = (unsigned)__shfl_xor((int)s0, 32);
        unsigned r1 = (unsigned)__shfl_xor((int)s1, 32);
        u32x4 bP;
        bP[0] = half ? r0 : pa0;  // B-frag keys kf*32 + t*16 + half*8 + {0..7}
        bP[1] = half ? r1 : pa1;
        bP[2] = half ? pb0 : r0;
        bP[3] = half ? pb1 : r1;
        #pragma unroll
        for (int f = 0; f < 2; ++f) {
          s16x8 aV = *(const s16x8*)&vs[(((kf * 2 + t) * 2 + f) * 64 + lane) * 8];
          oacc[f] = mfma32(aV, __builtin_bit_cast(s16x8, bP), oacc[f]);
        }
      }
    }
  }

  // epilogue: O^T D-layout -> O[b][ns][h][d]; regs q*4..q*4+3 are d contiguous
  const int b = bh >> 4, h = bh & 15;
  float inv = 1.f / l_i;
  size_t base = (((size_t)b * 2048 + qrow) * 16 + h) * 64;
  #pragma unroll
  for (int f = 0; f < 2; ++f)
    #pragma unroll
    for (int q = 0; q < 4; ++q) {
      int d0 = f * 32 + q * 8 + half * 4;
      uint2 o;
      o.x = pk_bf16(oacc[f][q * 4 + 0] * inv, oacc[f][q * 4 + 1] * inv);
      o.y = pk_bf16(oacc[f][q * 4 + 2] * inv, oacc[f][q * 4 + 3] * inv);
      *(uint2*)&O[base + d0] = o;
    }
}

// ---------- launch ----------

extern "C" void kernel_launch(void* const* d_in, const int* in_sizes, int n_in,
                              void* d_out, int out_size, void* d_ws, size_t ws_size,
                              hipStream_t stream) {
  (void)in_sizes; (void)n_in; (void)out_size; (void)ws_size;
  const float* x = (const float*)d_in[0];       // [4,2048,1024]
  const float* w_qkv = (const float*)d_in[1];   // [1024,3072]
  const float* w_proj = (const float*)d_in[2];  // [1024,1024]
  const float* b_proj = (const float*)d_in[3];  // [1024]
  float* out = (float*)d_out;
  char* ws = (char*)d_ws;
  const size_t MB = 1ull << 20;
  unsigned short* Xb  = (unsigned short*)(ws);            // 16MB (reused as Vt after QKV GEMM)
  unsigned short* Wqt = (unsigned short*)(ws + 16 * MB);  // 6MB  [3072][1024]
  unsigned short* Wpt = (unsigned short*)(ws + 22 * MB);  // 2MB  [1024][1024]
  unsigned short* Qb  = (unsigned short*)(ws + 24 * MB);  // 16MB [64 bh][2048][64]
  unsigned short* Kb  = (unsigned short*)(ws + 40 * MB);  // 16MB
  unsigned short* Vb  = (unsigned short*)(ws + 56 * MB);  // 16MB (reused as O after transpose_v)
  unsigned short* Vt  = Xb;  // Xb free after QKV GEMM
  unsigned short* Ob  = Vb;  // Vb free after transpose_v

  cvt_f32_bf16<<<2048, 256, 0, stream>>>((const float4*)x, Xb, 8388608 / 4);
  transpose_f32_bf16<<<dim3(96, 32), dim3(32, 8), 0, stream>>>(w_qkv, Wqt, 1024, 3072);
  transpose_f32_bf16<<<dim3(32, 32), dim3(32, 8), 0, stream>>>(w_proj, Wpt, 1024, 1024);

  // swapped orientation: A = weights (M=3072), Bt = X (N=8192)
  QKVEpi e1{Qb, Kb, Vb, 0.125f * 1.44269504088896340736f};
  gemm_bt<QKVEpi><<<dim3(64, 24), 256, 0, stream>>>(Wqt, Xb, 1024, e1);

  transpose_v<<<dim3(32, 64), 256, 0, stream>>>(Vb, Vt);
  flash_attn<<<dim3(16, 64), 256, 0, stream>>>(Qb, Kb, Vt, Ob);

  // swapped orientation: A = W_proj^T (M=1024), Bt = attention output (N=8192)
  ProjEpi e2{b_proj, out};
  gemm_bt<ProjEpi><<<dim3(64, 8), 256, 0, stream>>>(Wpt, Ob, 1024, e2);
}

// Round 8
// 279.453 us; speedup vs baseline: 1.0614x; 1.0614x over previous
//
#include <hip/hip_runtime.h>

typedef short s16x8 __attribute__((ext_vector_type(8)));
typedef float f32x4 __attribute__((ext_vector_type(4)));
typedef float f32x16 __attribute__((ext_vector_type(16)));
typedef unsigned u32x4 __attribute__((ext_vector_type(4)));

// ---------- helpers ----------

__device__ __forceinline__ unsigned short bf16bits(float f) {
  // round-to-nearest-even fp32 -> bf16 (finite inputs only)
  unsigned u = __builtin_bit_cast(unsigned, f);
  unsigned rnd = 0x7FFFu + ((u >> 16) & 1u);
  return (unsigned short)((u + rnd) >> 16);
}

__device__ __forceinline__ unsigned pk_bf16(float lo, float hi) {
  // dst[15:0]=bf16(lo), dst[31:16]=bf16(hi), RNE — one VALU op
  unsigned r;
  asm("v_cvt_pk_bf16_f32 %0, %1, %2" : "=v"(r) : "v"(lo), "v"(hi));
  return r;
}

__device__ __forceinline__ void async16(const void* g, void* l) {
  // global -> LDS direct copy, 16B per lane; LDS dest = wave-uniform base + lane*16
  __builtin_amdgcn_global_load_lds((const __attribute__((address_space(1))) void*)g,
                                   (__attribute__((address_space(3))) void*)l, 16, 0, 0);
}

__device__ __forceinline__ f32x4 mfma16(s16x8 a, s16x8 b, f32x4 c) {
  return __builtin_amdgcn_mfma_f32_16x16x32_bf16(a, b, c, 0, 0, 0);
}

__device__ __forceinline__ f32x16 mfma32(s16x8 a, s16x8 b, f32x16 c) {
  return __builtin_amdgcn_mfma_f32_32x32x16_bf16(a, b, c, 0, 0, 0);
}

// XOR-swizzled LDS tile: logical (row, col8) stored at unit row*U + (col8 ^ (row&(U-1)))
__device__ __forceinline__ s16x8 lds_frag(const unsigned short* S, int row, int c8, int U) {
  int unit = row * U + (c8 ^ (row & (U - 1)));
  return *(const s16x8*)(S + unit * 8);
}

// ---------- conversion / transpose kernels ----------

__global__ __launch_bounds__(256) void cvt_f32_bf16(const float4* __restrict__ in,
                                                    unsigned short* __restrict__ out, int n4) {
  int i = blockIdx.x * blockDim.x + threadIdx.x;
  int stride = gridDim.x * blockDim.x;
  for (; i < n4; i += stride) {
    float4 v = in[i];
    uint2 o;
    o.x = pk_bf16(v.x, v.y);
    o.y = pk_bf16(v.z, v.w);
    *(uint2*)(out + (size_t)i * 4) = o;
  }
}

// out[c][r] (bf16) = in[r][c] (fp32); R,C multiples of 32
__global__ __launch_bounds__(256) void transpose_f32_bf16(const float* __restrict__ in,
                                                          unsigned short* __restrict__ out,
                                                          int R, int C) {
  __shared__ float tile[32][33];
  int c0 = blockIdx.x * 32, r0 = blockIdx.y * 32;
  int tx = threadIdx.x, ty = threadIdx.y;  // (32, 8)
  #pragma unroll
  for (int i = 0; i < 32; i += 8)
    tile[ty + i][tx] = in[(size_t)(r0 + ty + i) * C + c0 + tx];
  __syncthreads();
  #pragma unroll
  for (int i = 0; i < 32; i += 8)
    out[(size_t)(c0 + ty + i) * R + r0 + tx] = bf16bits(tile[tx][ty + i]);
}

// V: [64 bh][2048][64] bf16 -> Vt: [64 bh][64][2048] bf16 (identity key order)
__global__ __launch_bounds__(256) void transpose_v(const unsigned short* __restrict__ V,
                                                   unsigned short* __restrict__ Vt) {
  __shared__ unsigned short sm[64 * 68];
  int bh = blockIdx.y, kt0 = blockIdx.x * 64;
  const unsigned short* v = V + (size_t)bh * 2048 * 64 + (size_t)kt0 * 64;  // 64x64 tile, contiguous
  unsigned short* vt = Vt + (size_t)bh * 64 * 2048;
  int t = threadIdx.x;
  #pragma unroll
  for (int i = 0; i < 4; ++i) {
    int u = i * 256 + t;        // uint2 index, 4 ushorts each
    int f = u * 4;              // flat = key*64 + d
    int k = f >> 6, d0 = f & 63;
    *(uint2*)&sm[k * 68 + d0] = *(const uint2*)&v[f];
  }
  __syncthreads();
  #pragma unroll
  for (int j = 0; j < 16; ++j) {
    int o = j * 256 + t;        // d*64 + k
    int d = o >> 6, k = o & 63;
    vt[(size_t)d * 2048 + kt0 + k] = sm[k * 68 + d];
  }
}

// ---------- GEMM: C[M,N] = A[M,K] @ Bt[N,K]^T, bf16 in, fp32 acc ----------
// Orientation chosen so M = "packed" output dim: epilogue functor gets 4
// consecutive-m accumulator values per lane (D-layout row axis) -> 8B/16B stores.

template <typename EPI>
__global__ __launch_bounds__(256) void gemm_bt(const unsigned short* __restrict__ A,
                                               const unsigned short* __restrict__ Bt,
                                               int K, EPI epi) {
  __shared__ __align__(16) unsigned short As[128 * 64];
  __shared__ __align__(16) unsigned short Bs[128 * 64];
  const int tid = threadIdx.x, wid = tid >> 6, lane = tid & 63;
  const int quad = lane >> 4, l16 = lane & 15;
  const int bm0 = blockIdx.y * 128, bn0 = blockIdx.x * 128;
  const int wm = (wid & 1) * 64, wn = (wid >> 1) * 64;
  f32x4 acc[4][4] = {};

  for (int kt = 0; kt < K; kt += 64) {
    #pragma unroll
    for (int t = 0; t < 4; ++t) {
      int c = wid * 4 + t;          // chunk 0..15, 1KB each
      int u = c * 64 + lane;        // physical 16B unit
      int row = u >> 3;
      int c8 = (u & 7) ^ (row & 7); // logical col8 (swizzle on fetch side)
      async16(A + (size_t)(bm0 + row) * K + kt + c8 * 8, (char*)As + c * 1024);
      async16(Bt + (size_t)(bn0 + row) * K + kt + c8 * 8, (char*)Bs + c * 1024);
    }
    __syncthreads();  // drains vmcnt before ds_read
    #pragma unroll
    for (int kk = 0; kk < 2; ++kk) {
      s16x8 a[4], b[4];
      #pragma unroll
      for (int i = 0; i < 4; ++i) a[i] = lds_frag(As, wm + i * 16 + l16, kk * 4 + quad, 8);
      #pragma unroll
      for (int j = 0; j < 4; ++j) b[j] = lds_frag(Bs, wn + j * 16 + l16, kk * 4 + quad, 8);
      #pragma unroll
      for (int i = 0; i < 4; ++i)
        #pragma unroll
        for (int j = 0; j < 4; ++j)
          acc[i][j] = mfma16(a[i], b[j], acc[i][j]);
    }
    __syncthreads();
  }
  // epilogue: per (i,j) one call, 4 consecutive m per lane
  #pragma unroll
  for (int i = 0; i < 4; ++i)
    #pragma unroll
    for (int j = 0; j < 4; ++j)
      epi.store4(bm0 + wm + i * 16 + quad * 4, bn0 + wn + j * 16 + l16, acc[i][j]);
}

// QKV (swapped orientation): m = qkv-dim (s*1024 + h*64 + d), n = x-row (b*2048+ns).
// 4 consecutive m = 4 consecutive d -> one 8B store into [bh][ns][64] layout.
struct QKVEpi {
  unsigned short *Q, *K, *V;  // each [64 bh][2048 ns][64 d]
  float qscale;               // hd^-0.5 * log2(e): folds softmax into exp2 domain
  __device__ __forceinline__ void store4(int m0, int n, f32x4 v) const {
    int s = m0 >> 10, h = (m0 >> 6) & 15, d = m0 & 63;
    int b = n >> 11, ns = n & 2047;
    unsigned short* dst = (s == 0) ? Q : ((s == 1) ? K : V);
    float sc = (s == 0) ? qscale : 1.f;
    uint2 o;
    o.x = pk_bf16(v[0] * sc, v[1] * sc);
    o.y = pk_bf16(v[2] * sc, v[3] * sc);
    *(uint2*)&dst[(((size_t)b * 16 + h) * 2048 + ns) * 64 + d] = o;
  }
};

// Proj (swapped orientation): m = out-col, n = x-row. One float4 store + float4 bias.
struct ProjEpi {
  const float* bias;
  float* out;
  __device__ __forceinline__ void store4(int m0, int n, f32x4 v) const {
    float4 b4 = *(const float4*)&bias[m0];
    float4 o = {v[0] + b4.x, v[1] + b4.y, v[2] + b4.z, v[3] + b4.w};
    *(float4*)&out[(size_t)n * 1024 + m0] = o;
  }
};

// ---------- flash attention ----------
// S^T form, register-resident P, max-free softmax, double-buffered staging
// (one barrier per tile), 32 q-rows per wave, fragment-major LDS staging
// (zero bank conflicts). P B-frag via half-swap dword shuffle (known-good).
// XCD-aware block swizzle: all 16 q-tiles of a bh share bid%8 -> same XCD
// under round-robin dispatch (K/V stay in that XCD's L2).
// Q,K: [64 bh][2048][64] bf16 (Q pre-scaled by hd^-0.5*log2e);  Vt: [64 bh][64][2048]
// O: [4][2048][16][64] bf16.
__global__ __launch_bounds__(256, 4) void flash_attn(const unsigned short* __restrict__ Q,
                                                     const unsigned short* __restrict__ K,
                                                     const unsigned short* __restrict__ Vt,
                                                     unsigned short* __restrict__ O) {
  __shared__ __align__(16) unsigned short Ks[2][8 * 512];  // dbuf, 8 chunks (kf,s) of 64 frags
  __shared__ __align__(16) unsigned short Vs[2][8 * 512];  // dbuf, 8 chunks (ktstep,f)
  const int tid = threadIdx.x, wid = tid >> 6, lane = tid & 63;
  const int l31 = lane & 31, half = lane >> 5;
  // XCD swizzle: bijection bid -> (bh, qt); all blocks of a bh share bid&7
  const int bid = blockIdx.y * gridDim.x + blockIdx.x;  // 0..1023
  const int xcd = bid & 7, idx = bid >> 3;
  const int bh = xcd * 8 + (idx & 7);
  const int qt = idx >> 3;
  const unsigned short* Qg = Q + (size_t)bh * 2048 * 64;
  const unsigned short* Kg = K + (size_t)bh * 2048 * 64;
  const unsigned short* Vg = Vt + (size_t)bh * 64 * 2048;
  const int qrow = qt * 128 + wid * 32 + l31;  // this lane's q-row

  // Q as B-operand fragments: B[k=d][n=qrow]; lane holds d = s*16 + half*8 + j
  s16x8 qB[4];
  #pragma unroll
  for (int s = 0; s < 4; ++s)
    qB[s] = *(const s16x8*)&Qg[(size_t)qrow * 64 + s * 16 + half * 8];

  // staging: waves 0,1 stage K chunks 0..7 (kf=c>>2, s=c&3); waves 2,3 stage V
  // chunks 0..7 (ktstep=c>>1, f=c&1). Lane fetches exactly its fragment source.
  const bool isK = wid < 2;
  int sA[4];
  #pragma unroll
  for (int t = 0; t < 4; ++t) {
    int c = (wid & 1) * 4 + t;
    if (isK) sA[t] = ((c >> 2) * 32 + l31) * 64 + ((c & 3) * 2 + half) * 8;
    else     sA[t] = ((c & 1) * 32 + l31) * 2048 + (c >> 1) * 16 + half * 8;
  }

  auto stage = [&](int kt, int buf) {
    const int kb = kt * 64;
    #pragma unroll
    for (int t = 0; t < 4; ++t) {
      int c = (wid & 1) * 4 + t;
      if (isK) async16(Kg + (size_t)kb * 64 + sA[t], (char*)&Ks[buf][0] + c * 1024);
      else     async16(Vg + kb + sA[t],              (char*)&Vs[buf][0] + c * 1024);
    }
  };

  f32x16 oacc[2] = {};  // [f]: O^T[d = f*32 + (r&3)+8*(r>>2)+4*half][qrow]
  float l_i = 0.f;
  const f32x16 fz = {};

  stage(0, 0);
  for (int kt = 0; kt < 32; ++kt) {
    const int cur = kt & 1;
    __syncthreads();  // tile kt visible to all; buf cur^1 free (all done with kt-1)
    if (kt + 1 < 32) stage(kt + 1, cur ^ 1);  // in flight across this tile's compute
    const unsigned short* ks = &Ks[cur][0];
    const unsigned short* vs = &Vs[cur][0];

    #pragma unroll
    for (int kf = 0; kf < 2; ++kf) {  // 32-key chunk: QK -> softmax -> PV
      // S^T = K @ Q^T; A-frag: keys kf*32 + (r&3)+8*(r>>2)+4*half, col = qrow
      f32x16 st;
      {
        s16x8 a = *(const s16x8*)&ks[((kf * 4 + 0) * 64 + lane) * 8];
        st = mfma32(a, qB[0], fz);
      }
      #pragma unroll
      for (int s = 1; s < 4; ++s) {
        s16x8 a = *(const s16x8*)&ks[((kf * 4 + s) * 64 + lane) * 8];
        st = mfma32(a, qB[s], st);
      }
      // max-free softmax (scores bounded; fp32 can't overflow), tree-reduced sum
      float a0 = 0.f, a1 = 0.f, a2 = 0.f, a3 = 0.f;
      #pragma unroll
      for (int r = 0; r < 16; r += 4) {
        float p0 = __builtin_amdgcn_exp2f(st[r + 0]);
        float p1 = __builtin_amdgcn_exp2f(st[r + 1]);
        float p2 = __builtin_amdgcn_exp2f(st[r + 2]);
        float p3 = __builtin_amdgcn_exp2f(st[r + 3]);
        st[r + 0] = p0; st[r + 1] = p1; st[r + 2] = p2; st[r + 3] = p3;
        a0 += p0; a1 += p1; a2 += p2; a3 += p3;
      }
      float rs = (a0 + a1) + (a2 + a3);
      rs += __shfl_xor(rs, 32);
      l_i += rs;
      // pack P to bf16 B-frags (half-swap via dword shuffle) + PV
      #pragma unroll
      for (int t = 0; t < 2; ++t) {  // 16-key step within chunk
        int rb = t * 8;
        unsigned pa0 = pk_bf16(st[rb + 0], st[rb + 1]);
        unsigned pa1 = pk_bf16(st[rb + 2], st[rb + 3]);
        unsigned pb0 = pk_bf16(st[rb + 4], st[rb + 5]);
        unsigned pb1 = pk_bf16(st[rb + 6], st[rb + 7]);
        unsigned s0 = half ? pa0 : pb0;
        unsigned s1 = half ? pa1 : pb1;
        unsigned r0 = (unsigned)__shfl_xor((int)s0, 32);
        unsigned r1 = (unsigned)__shfl_xor((int)s1, 32);
        u32x4 bP;
        bP[0] = half ? r0 : pa0;  // B-frag keys kf*32 + t*16 + half*8 + {0..7}
        bP[1] = half ? r1 : pa1;
        bP[2] = half ? pb0 : r0;
        bP[3] = half ? pb1 : r1;
        #pragma unroll
        for (int f = 0; f < 2; ++f) {
          s16x8 aV = *(const s16x8*)&vs[(((kf * 2 + t) * 2 + f) * 64 + lane) * 8];
          oacc[f] = mfma32(aV, __builtin_bit_cast(s16x8, bP), oacc[f]);
        }
      }
    }
  }

  // epilogue: O^T D-layout -> O[b][ns][h][d]; regs q*4..q*4+3 are d contiguous
  const int b = bh >> 4, h = bh & 15;
  float inv = 1.f / l_i;
  size_t base = (((size_t)b * 2048 + qrow) * 16 + h) * 64;
  #pragma unroll
  for (int f = 0; f < 2; ++f)
    #pragma unroll
    for (int q = 0; q < 4; ++q) {
      int d0 = f * 32 + q * 8 + half * 4;
      uint2 o;
      o.x = pk_bf16(oacc[f][q * 4 + 0] * inv, oacc[f][q * 4 + 1] * inv);
      o.y = pk_bf16(oacc[f][q * 4 + 2] * inv, oacc[f][q * 4 + 3] * inv);
      *(uint2*)&O[base + d0] = o;
    }
}

// ---------- launch ----------

extern "C" void kernel_launch(void* const* d_in, const int* in_sizes, int n_in,
                              void* d_out, int out_size, void* d_ws, size_t ws_size,
                              hipStream_t stream) {
  (void)in_sizes; (void)n_in; (void)out_size; (void)ws_size;
  const float* x = (const float*)d_in[0];       // [4,2048,1024]
  const float* w_qkv = (const float*)d_in[1];   // [1024,3072]
  const float* w_proj = (const float*)d_in[2];  // [1024,1024]
  const float* b_proj = (const float*)d_in[3];  // [1024]
  float* out = (float*)d_out;
  char* ws = (char*)d_ws;
  const size_t MB = 1ull << 20;
  unsigned short* Xb  = (unsigned short*)(ws);            // 16MB (reused as Vt after QKV GEMM)
  unsigned short* Wqt = (unsigned short*)(ws + 16 * MB);  // 6MB  [3072][1024]
  unsigned short* Wpt = (unsigned short*)(ws + 22 * MB);  // 2MB  [1024][1024]
  unsigned short* Qb  = (unsigned short*)(ws + 24 * MB);  // 16MB [64 bh][2048][64]
  unsigned short* Kb  = (unsigned short*)(ws + 40 * MB);  // 16MB
  unsigned short* Vb  = (unsigned short*)(ws + 56 * MB);  // 16MB (reused as O after transpose_v)
  unsigned short* Vt  = Xb;  // Xb free after QKV GEMM
  unsigned short* Ob  = Vb;  // Vb free after transpose_v

  cvt_f32_bf16<<<2048, 256, 0, stream>>>((const float4*)x, Xb, 8388608 / 4);
  transpose_f32_bf16<<<dim3(96, 32), dim3(32, 8), 0, stream>>>(w_qkv, Wqt, 1024, 3072);
  transpose_f32_bf16<<<dim3(32, 32), dim3(32, 8), 0, stream>>>(w_proj, Wpt, 1024, 1024);

  // swapped orientation: A = weights (M=3072), Bt = X (N=8192)
  QKVEpi e1{Qb, Kb, Vb, 0.125f * 1.44269504088896340736f};
  gemm_bt<QKVEpi><<<dim3(64, 24), 256, 0, stream>>>(Wqt, Xb, 1024, e1);

  transpose_v<<<dim3(32, 64), 256, 0, stream>>>(Vb, Vt);
  flash_attn<<<dim3(16, 64), 256, 0, stream>>>(Qb, Kb, Vt, Ob);

  // swapped orientation: A = W_proj^T (M=1024), Bt = attention output (N=8192)
  ProjEpi e2{b_proj, out};
  gemm_bt<ProjEpi><<<dim3(64, 8), 256, 0, stream>>>(Wpt, Ob, 1024, e2);
}